// Round 1
// baseline (603.866 us; speedup 1.0000x reference)
//
#include <hip/hip_runtime.h>
#include <hip/hip_bf16.h>

// Problem constants (fixed by the reference).
#define BSZ 4
#define SEQ 512
#define DMODEL 512
#define NHEAD 8
#define DKH 64
#define EPSLN 1e-6f

// ---------------------------------------------------------------------------
// Generic fp32 GEMM + bias: C[M,N] = A[M,K] @ W[K,N] + bias[N]
// 64x64 block tile, 256 threads, 4x4 register tile, K-step 16.
// ---------------------------------------------------------------------------
__global__ __launch_bounds__(256) void gemm_bias_kernel(
    const float* __restrict__ A, const float* __restrict__ W,
    const float* __restrict__ bias, float* __restrict__ C,
    int M, int N, int K) {
  __shared__ __align__(16) float As[16][64];
  __shared__ __align__(16) float Bs[16][64];
  const int tid = threadIdx.x;
  const int tx = tid & 15, ty = tid >> 4;
  const int bn = blockIdx.x * 64, bm = blockIdx.y * 64;

  float acc[4][4] = {};

  const int lm = tid >> 2;          // 0..63  (A row within tile)
  const int lk4 = (tid & 3) * 4;    // 0,4,8,12 (A k within tile)
  const int bn4 = (tid & 15) * 4;   // B col within tile
  const int bkk = tid >> 4;         // B k within tile

  for (int k0 = 0; k0 < K; k0 += 16) {
    float4 av = *(const float4*)&A[(size_t)(bm + lm) * K + k0 + lk4];
    As[lk4 + 0][lm] = av.x;
    As[lk4 + 1][lm] = av.y;
    As[lk4 + 2][lm] = av.z;
    As[lk4 + 3][lm] = av.w;
    *(float4*)&Bs[bkk][bn4] =
        *(const float4*)&W[(size_t)(k0 + bkk) * N + bn + bn4];
    __syncthreads();
#pragma unroll
    for (int kk = 0; kk < 16; ++kk) {
      float4 a4 = *(const float4*)&As[kk][ty * 4];
      float4 b4 = *(const float4*)&Bs[kk][tx * 4];
      acc[0][0] += a4.x * b4.x; acc[0][1] += a4.x * b4.y;
      acc[0][2] += a4.x * b4.z; acc[0][3] += a4.x * b4.w;
      acc[1][0] += a4.y * b4.x; acc[1][1] += a4.y * b4.y;
      acc[1][2] += a4.y * b4.z; acc[1][3] += a4.y * b4.w;
      acc[2][0] += a4.z * b4.x; acc[2][1] += a4.z * b4.y;
      acc[2][2] += a4.z * b4.z; acc[2][3] += a4.z * b4.w;
      acc[3][0] += a4.w * b4.x; acc[3][1] += a4.w * b4.y;
      acc[3][2] += a4.w * b4.z; acc[3][3] += a4.w * b4.w;
    }
    __syncthreads();
  }
  const float4 bv = *(const float4*)&bias[bn + tx * 4];
#pragma unroll
  for (int i = 0; i < 4; ++i) {
    float4 o;
    o.x = acc[i][0] + bv.x;
    o.y = acc[i][1] + bv.y;
    o.z = acc[i][2] + bv.z;
    o.w = acc[i][3] + bv.w;
    *(float4*)&C[(size_t)(bm + ty * 4 + i) * N + bn + tx * 4] = o;
  }
}

// ---------------------------------------------------------------------------
// Fused attention core. One block per (b, h, 16-row i-tile). 256 threads.
//   Phase A: Ssum[i][j] = sum_c exp(q_b[i] . k_c[j]) in LDS; diagonal exps
//            (c==b) kept in registers; R = diag/(8*Ssum) written to global ws.
//   Phase B: for each c: score[i][d] = sum_j R[i][j]*V_c[j][d]; softmax over
//            d(64); LN (unbiased std, eps on std); accumulate over c; +4*qh.
// Thread mapping (both phases): tx = tid&15 -> 4 consecutive cols, ty = tid>>4
// -> row i. 64-wide row reductions = 16-lane shuffle groups x 4 regs.
// LDS: 33 KB Ssum (pad 516) + 17.4 KB KV staging + 4 KB q tile = 54.5 KB.
// ---------------------------------------------------------------------------
__global__ __launch_bounds__(256) void attn_kernel(
    const float* __restrict__ Qp, const float* __restrict__ Kp,
    const float* __restrict__ Vp, const float* __restrict__ alpha,
    const float* __restrict__ beta, float* __restrict__ Rws,
    float* __restrict__ Hc) {
  const int it = blockIdx.x;   // i-tile (0..31)
  const int h = blockIdx.y;    // head
  const int b = blockIdx.z;    // q batch
  const int i0 = it * 16;
  const int tid = threadIdx.x;
  const int tx = tid & 15, ty = tid >> 4;

  __shared__ __align__(16) float qs[16][64];
  __shared__ __align__(16) float Ssum[16 * 516];   // pad 512->516
  __shared__ __align__(16) float KV[64 * 68];      // K (transposed) / V tile

  // Load q tile (coalesced), zero Ssum.
  {
    const int d = tid & 63, ir = tid >> 6;
#pragma unroll
    for (int r = 0; r < 4; ++r) {
      const int i = ir * 4 + r;
      qs[i][d] = Qp[(size_t)(b * SEQ + i0 + i) * DMODEL + h * DKH + d];
    }
  }
  for (int l = tid; l < 16 * 516; l += 256) Ssum[l] = 0.0f;
  __syncthreads();

  float ebb[32];  // exp scores for c==b: [jt][u], jt<8, u<4

  // ---------------- Phase A: scores/exp/sums ----------------
  for (int c = 0; c < BSZ; ++c) {
#pragma unroll
    for (int jt = 0; jt < 8; ++jt) {
      const int j0 = jt * 64;
      {  // stage K tile transposed: KV[d*68 + jj]
        const int d4 = (tid & 15) * 4;
        const int jb = tid >> 4;
#pragma unroll
        for (int p = 0; p < 4; ++p) {
          const int jj = jb + p * 16;
          const float4 k4 =
              *(const float4*)&Kp[(size_t)(c * SEQ + j0 + jj) * DMODEL + h * DKH + d4];
          KV[(d4 + 0) * 68 + jj] = k4.x;
          KV[(d4 + 1) * 68 + jj] = k4.y;
          KV[(d4 + 2) * 68 + jj] = k4.z;
          KV[(d4 + 3) * 68 + jj] = k4.w;
        }
      }
      __syncthreads();
      float a0 = 0.f, a1 = 0.f, a2 = 0.f, a3 = 0.f;
#pragma unroll
      for (int d = 0; d < 64; d += 4) {
        const float4 a4 = *(const float4*)&qs[ty][d];
        const float* kvp = &KV[d * 68 + tx * 4];
        const float4 b0 = *(const float4*)(kvp);
        const float4 b1 = *(const float4*)(kvp + 68);
        const float4 b2 = *(const float4*)(kvp + 136);
        const float4 b3 = *(const float4*)(kvp + 204);
        a0 += a4.x * b0.x + a4.y * b1.x + a4.z * b2.x + a4.w * b3.x;
        a1 += a4.x * b0.y + a4.y * b1.y + a4.z * b2.y + a4.w * b3.y;
        a2 += a4.x * b0.z + a4.y * b1.z + a4.z * b2.z + a4.w * b3.z;
        a3 += a4.x * b0.w + a4.y * b1.w + a4.z * b2.w + a4.w * b3.w;
      }
      const float e0 = expf(a0), e1 = expf(a1), e2 = expf(a2), e3 = expf(a3);
      const int sb = ty * 516 + j0 + tx * 4;
      Ssum[sb + 0] += e0;   // unique owner per (i,j): no atomics needed
      Ssum[sb + 1] += e1;
      Ssum[sb + 2] += e2;
      Ssum[sb + 3] += e3;
      if (c == b) {
        ebb[jt * 4 + 0] = e0;
        ebb[jt * 4 + 1] = e1;
        ebb[jt * 4 + 2] = e2;
        ebb[jt * 4 + 3] = e3;
      }
      __syncthreads();
    }
  }

  // R = diag/(8*Ssum) -> global workspace (row per (b,h,i), coalesced).
  const size_t rrow = ((size_t)(b * NHEAD + h) * SEQ + i0 + ty) * SEQ;
  {
#pragma unroll
    for (int jt = 0; jt < 8; ++jt) {
      const int j0 = jt * 64 + tx * 4;
      const int sb = ty * 516 + j0;
      float4 r4;
      r4.x = ebb[jt * 4 + 0] / (8.0f * Ssum[sb + 0]);
      r4.y = ebb[jt * 4 + 1] / (8.0f * Ssum[sb + 1]);
      r4.z = ebb[jt * 4 + 2] / (8.0f * Ssum[sb + 2]);
      r4.w = ebb[jt * 4 + 3] / (8.0f * Ssum[sb + 3]);
      *(float4*)&Rws[rrow + j0] = r4;
    }
  }

  const float4 al = *(const float4*)&alpha[tx * 4];
  const float4 be = *(const float4*)&beta[tx * 4];
  float h0 = 0.f, h1 = 0.f, h2 = 0.f, h3 = 0.f;

  // ---------------- Phase B: RV + softmax + LN, accumulate over c ----------
  for (int c = 0; c < BSZ; ++c) {
    float s0 = 0.f, s1 = 0.f, s2 = 0.f, s3 = 0.f;
#pragma unroll
    for (int jt = 0; jt < 8; ++jt) {
      const int j0 = jt * 64;
      __syncthreads();  // protect KV from previous tile's readers
      {  // stage V tile: KV[jj*68 + d]
        const int d4 = (tid & 15) * 4;
        const int jb = tid >> 4;
#pragma unroll
        for (int p = 0; p < 4; ++p) {
          const int jj = jb + p * 16;
          *(float4*)&KV[jj * 68 + d4] =
              *(const float4*)&Vp[(size_t)(c * SEQ + j0 + jj) * DMODEL + h * DKH + d4];
        }
      }
      __syncthreads();
#pragma unroll
      for (int jj = 0; jj < 64; jj += 4) {
        const float4 r4 = *(const float4*)&Rws[rrow + j0 + jj];  // L2-resident
        const float* kvp = &KV[jj * 68 + tx * 4];
        const float4 v0 = *(const float4*)(kvp);
        const float4 v1 = *(const float4*)(kvp + 68);
        const float4 v2 = *(const float4*)(kvp + 136);
        const float4 v3 = *(const float4*)(kvp + 204);
        s0 += r4.x * v0.x + r4.y * v1.x + r4.z * v2.x + r4.w * v3.x;
        s1 += r4.x * v0.y + r4.y * v1.y + r4.z * v2.y + r4.w * v3.y;
        s2 += r4.x * v0.z + r4.y * v1.z + r4.z * v2.z + r4.w * v3.z;
        s3 += r4.x * v0.w + r4.y * v1.w + r4.z * v2.w + r4.w * v3.w;
      }
    }
    // Row (i=ty) spreads over 16 tx lanes x 4 regs -> 16-lane shuffle groups.
    float mx = fmaxf(fmaxf(s0, s1), fmaxf(s2, s3));
#pragma unroll
    for (int m = 8; m >= 1; m >>= 1) mx = fmaxf(mx, __shfl_xor(mx, m));
    float x0 = expf(s0 - mx), x1 = expf(s1 - mx);
    float x2 = expf(s2 - mx), x3 = expf(s3 - mx);
    float es = x0 + x1 + x2 + x3;
#pragma unroll
    for (int m = 8; m >= 1; m >>= 1) es += __shfl_xor(es, m);
    const float inv = 1.0f / es;
    x0 *= inv; x1 *= inv; x2 *= inv; x3 *= inv;
    float sum = x0 + x1 + x2 + x3;
#pragma unroll
    for (int m = 8; m >= 1; m >>= 1) sum += __shfl_xor(sum, m);
    const float mu = sum * (1.0f / 64.0f);
    const float d0 = x0 - mu, d1 = x1 - mu, d2 = x2 - mu, d3 = x3 - mu;
    float sq = d0 * d0 + d1 * d1 + d2 * d2 + d3 * d3;
#pragma unroll
    for (int m = 8; m >= 1; m >>= 1) sq += __shfl_xor(sq, m);
    const float sd = sqrtf(sq * (1.0f / 63.0f));  // unbiased (ddof=1)
    const float rs = 1.0f / (sd + EPSLN);         // eps on std, not var
    h0 += al.x * d0 * rs + be.x;
    h1 += al.y * d1 * rs + be.y;
    h2 += al.z * d2 * rs + be.z;
    h3 += al.w * d3 * rs + be.w;
  }

  // heads += 4*qh; write concat layout [b, i, h*64+d]
  {
    const float4 q4 = *(const float4*)&qs[ty][tx * 4];
    float4 o;
    o.x = h0 + 4.0f * q4.x;
    o.y = h1 + 4.0f * q4.y;
    o.z = h2 + 4.0f * q4.z;
    o.w = h3 + 4.0f * q4.w;
    *(float4*)&Hc[(size_t)(b * SEQ + i0 + ty) * DMODEL + h * DKH + tx * 4] = o;
  }
}

// ---------------------------------------------------------------------------
extern "C" void kernel_launch(void* const* d_in, const int* in_sizes, int n_in,
                              void* d_out, int out_size, void* d_ws,
                              size_t ws_size, hipStream_t stream) {
  (void)in_sizes; (void)n_in; (void)out_size; (void)ws_size;
  const float* q = (const float*)d_in[0];
  const float* k = (const float*)d_in[1];
  const float* v = (const float*)d_in[2];
  const float* Wq = (const float*)d_in[3];
  const float* bq = (const float*)d_in[4];
  const float* Wk = (const float*)d_in[5];
  const float* bk = (const float*)d_in[6];
  const float* Wv = (const float*)d_in[7];
  const float* bv = (const float*)d_in[8];
  const float* Wo = (const float*)d_in[9];
  const float* bo = (const float*)d_in[10];
  const float* alpha = (const float*)d_in[11];
  const float* beta = (const float*)d_in[12];
  float* out = (float*)d_out;

  // Workspace layout (floats): Qp | Kp | Vp | Hc (1M each) | Rws (8M) = 48 MB
  float* wsf = (float*)d_ws;
  float* Qp = wsf + 0 * (1u << 20);
  float* Kp = wsf + 1 * (1u << 20);
  float* Vp = wsf + 2 * (1u << 20);
  float* Hc = wsf + 3 * (1u << 20);
  float* Rws = wsf + 4 * (size_t)(1u << 20);

  const int M = BSZ * SEQ, N = DMODEL, K = DMODEL;
  dim3 ggrid(N / 64, M / 64);
  gemm_bias_kernel<<<ggrid, 256, 0, stream>>>(q, Wq, bq, Qp, M, N, K);
  gemm_bias_kernel<<<ggrid, 256, 0, stream>>>(k, Wk, bk, Kp, M, N, K);
  gemm_bias_kernel<<<ggrid, 256, 0, stream>>>(v, Wv, bv, Vp, M, N, K);
  attn_kernel<<<dim3(SEQ / 16, NHEAD, BSZ), 256, 0, stream>>>(
      Qp, Kp, Vp, alpha, beta, Rws, Hc);
  gemm_bias_kernel<<<ggrid, 256, 0, stream>>>(Hc, Wo, bo, out, M, N, K);
}

// Round 2
// 208.387 us; speedup vs baseline: 2.8978x; 2.8978x over previous
//
#include <hip/hip_runtime.h>
#include <hip/hip_bf16.h>

// Problem constants (fixed by the reference).
#define BSZ 4
#define SEQ 512
#define DMODEL 512
#define NHEAD 8
#define DKH 64
#define EPSLN 1e-6f

typedef short bf16x8 __attribute__((ext_vector_type(8)));
typedef float f32x4 __attribute__((ext_vector_type(4)));

// fp32 -> bf16 round-to-nearest-even
static __device__ __forceinline__ short f2bf(float x) {
  unsigned u = __builtin_bit_cast(unsigned, x);
  u = (u + 0x7FFFu + ((u >> 16) & 1u)) >> 16;
  return (short)u;
}
static __device__ __forceinline__ bf16x8 cvt8(float4 a, float4 b) {
  bf16x8 r;
  r[0] = f2bf(a.x); r[1] = f2bf(a.y); r[2] = f2bf(a.z); r[3] = f2bf(a.w);
  r[4] = f2bf(b.x); r[5] = f2bf(b.y); r[6] = f2bf(b.z); r[7] = f2bf(b.w);
  return r;
}
static __device__ __forceinline__ unsigned pk2(float a, float b) {
  return (unsigned)(unsigned short)f2bf(a) |
         ((unsigned)(unsigned short)f2bf(b) << 16);
}

// ---------------------------------------------------------------------------
// W (fp32, [K=512][N=512]) -> W^T (bf16, [N][K]) so GEMM B-fragments are
// contiguous-k 16B global loads. LDS tile transpose, 64x64 per block.
// ---------------------------------------------------------------------------
__global__ __launch_bounds__(256) void wcast_kernel(
    const float* __restrict__ Wq, const float* __restrict__ Wk,
    const float* __restrict__ Wv, const float* __restrict__ Wo,
    short* __restrict__ Wqt, short* __restrict__ Wkt,
    short* __restrict__ Wvt, short* __restrict__ Wot) {
  __shared__ float T[64][65];
  const float* src; short* dst;
  switch (blockIdx.z) {
    case 0: src = Wq; dst = Wqt; break;
    case 1: src = Wk; dst = Wkt; break;
    case 2: src = Wv; dst = Wvt; break;
    default: src = Wo; dst = Wot; break;
  }
  const int k0 = blockIdx.x * 64, n0 = blockIdx.y * 64;
  const int tid = threadIdx.x;
  const int n4 = (tid & 15) * 4, kk = tid >> 4;
#pragma unroll
  for (int p = 0; p < 4; ++p) {
    float4 v = *(const float4*)&src[(size_t)(k0 + kk + p * 16) * DMODEL + n0 + n4];
    T[kk + p * 16][n4 + 0] = v.x;
    T[kk + p * 16][n4 + 1] = v.y;
    T[kk + p * 16][n4 + 2] = v.z;
    T[kk + p * 16][n4 + 3] = v.w;
  }
  __syncthreads();
  const int k4 = (tid & 15) * 4;
#pragma unroll
  for (int p = 0; p < 4; ++p) {
    const int nn = (tid >> 4) + p * 16;
    float x0 = T[k4 + 0][nn], x1 = T[k4 + 1][nn];
    float x2 = T[k4 + 2][nn], x3 = T[k4 + 3][nn];
    uint2 u; u.x = pk2(x0, x1); u.y = pk2(x2, x3);
    *(uint2*)&dst[(size_t)(n0 + nn) * DMODEL + k0 + k4] = u;
  }
}

// ---------------------------------------------------------------------------
// MFMA GEMM: C = A(fp32)[M][K] @ W(bf16,[N][K] transposed) + bias.
// 64x64 block, 4 waves (16 rows x 64 cols each). No LDS, no barriers:
// A-frag = 32B global fp32 + cvt; B-frag = 16B global bf16.
// OMODE 0: fp32 [M][N]; 1: bf16 [M][N]; 2: bf16 Vt[c][h][d][j] scatter.
// ---------------------------------------------------------------------------
template <int OMODE>
__global__ __launch_bounds__(256, 4) void gemm_mfma(
    const float* __restrict__ A, const short* __restrict__ Wt,
    const float* __restrict__ bias, void* __restrict__ Cout,
    int M, int N, int K) {
  const int tid = threadIdx.x;
  const int w = tid >> 6, lane = tid & 63;
  const int l15 = lane & 15, q = lane >> 4;
  const int bn = blockIdx.x * 64, bm = blockIdx.y * 64;

  f32x4 acc[4] = {};
  const float* ap = A + (size_t)(bm + w * 16 + l15) * K + q * 8;
  const short* wp = Wt + (size_t)(bn + l15) * K + q * 8;

#pragma unroll 4
  for (int k0 = 0; k0 < K; k0 += 32) {
    float4 a0 = *(const float4*)(ap);
    float4 a1 = *(const float4*)(ap + 4);
    bf16x8 af = cvt8(a0, a1);
#pragma unroll
    for (int nt = 0; nt < 4; ++nt) {
      bf16x8 bf = *(const bf16x8*)(wp + (size_t)nt * 16 * K);
      acc[nt] = __builtin_amdgcn_mfma_f32_16x16x32_bf16(af, bf, acc[nt], 0, 0, 0);
    }
    ap += 32; wp += 32;
  }

#pragma unroll
  for (int nt = 0; nt < 4; ++nt) {
    const int col = bn + nt * 16 + l15;
    const float bv = bias[col];
#pragma unroll
    for (int r = 0; r < 4; ++r) {
      const int orow = bm + w * 16 + q * 4 + r;
      const float val = acc[nt][r] + bv;
      if (OMODE == 0) {
        ((float*)Cout)[(size_t)orow * N + col] = val;
      } else if (OMODE == 1) {
        ((short*)Cout)[(size_t)orow * N + col] = f2bf(val);
      } else {
        // V: token orow = c*512+j, col = h*64+d -> Vt[((c*8+h)*64+d)*512 + j]
        const int cc = orow >> 9, j = orow & 511;
        const int hh = col >> 6, d = col & 63;
        ((short*)Cout)[(((size_t)(cc * 8 + hh) * 64 + d) << 9) + j] = f2bf(val);
      }
    }
  }
}

// ---------------------------------------------------------------------------
// Fused attention, MFMA. Block = (16 q-rows, head h, batch b), 4 waves.
// Phase A: S = Qh[16x64] @ K_c^T via MFMA (B-frag straight from bf16 K rows);
//   exp in regs; per-lane sacc[32] accumulates sum_c (owner lane is identical
//   for all c), ebb[32] keeps the diagonal c==b exps. No LDS, no barriers.
// R = ebb/(8*sacc) -> bf16 LDS tile Rs[16][520] (A-operand layout for RV).
// Phase B: score[16][c*64+d] = R @ Vstack; wave w owns c=w; B-frag straight
//   from pre-transposed bf16 Vt[c][h][d][j]. Softmax(d=64): mean is exactly
//   1/64; unbiased-std LN; per-wave results exchanged through hb, summed,
//   +4*qh residual. 34 KB LDS, 2 barriers total.
// ---------------------------------------------------------------------------
__global__ __launch_bounds__(256, 4) void attn_mfma(
    const float* __restrict__ Qp, const short* __restrict__ Kb,
    const short* __restrict__ Vt, const float* __restrict__ alpha,
    const float* __restrict__ beta, float* __restrict__ Hc) {
  __shared__ __align__(16) short Rs[16][520];     // 16640 B (pad 512->520)
  __shared__ __align__(16) float hb[4 * 16 * 68]; // 17408 B

  const int it = blockIdx.x, h = blockIdx.y, b = blockIdx.z;
  const int i0 = it * 16;
  const int tid = threadIdx.x;
  const int w = tid >> 6, lane = tid & 63;
  const int l15 = lane & 15, q = lane >> 4;

  // Q A-fragments (rows i0+l15), fp32 global -> bf16, reused for all c,jt.
  const float* qrow = Qp + (size_t)(b * SEQ + i0 + l15) * DMODEL + h * DKH;
  float4 q0 = *(const float4*)(qrow + q * 8);
  float4 q1 = *(const float4*)(qrow + q * 8 + 4);
  float4 q2 = *(const float4*)(qrow + 32 + q * 8);
  float4 q3 = *(const float4*)(qrow + 32 + q * 8 + 4);
  const bf16x8 aq0 = cvt8(q0, q1), aq1 = cvt8(q2, q3);

  float sacc[32];   // sum over c of exp scores, this lane's 32 (i,j) cells
  float ebb[32];    // exp scores for c == b
#pragma unroll
  for (int x = 0; x < 32; ++x) sacc[x] = 0.0f;

  // ---------------- Phase A ----------------
  for (int c = 0; c < BSZ; ++c) {
    const short* kbase = Kb + ((size_t)(c * SEQ) * DMODEL) + h * DKH + q * 8;
#pragma unroll
    for (int jt = 0; jt < 8; ++jt) {
      const int j = jt * 64 + w * 16 + l15;     // this lane's score column
      const short* kr = kbase + (size_t)j * DMODEL;
      bf16x8 bk0 = *(const bf16x8*)(kr);
      bf16x8 bk1 = *(const bf16x8*)(kr + 32);
      f32x4 s = {};
      s = __builtin_amdgcn_mfma_f32_16x16x32_bf16(aq0, bk0, s, 0, 0, 0);
      s = __builtin_amdgcn_mfma_f32_16x16x32_bf16(aq1, bk1, s, 0, 0, 0);
#pragma unroll
      for (int r = 0; r < 4; ++r) {
        const float e = __expf(s[r]);           // scores ~N(0,1.6): safe
        sacc[jt * 4 + r] += e;
        if (c == b) ebb[jt * 4 + r] = e;
      }
    }
  }

  // R = diag / (8 * sum_c), straight into A-operand bf16 LDS tile.
#pragma unroll
  for (int jt = 0; jt < 8; ++jt) {
    const int col = jt * 64 + w * 16 + l15;
#pragma unroll
    for (int r = 0; r < 4; ++r)
      Rs[q * 4 + r][col] = f2bf(ebb[jt * 4 + r] / (8.0f * sacc[jt * 4 + r]));
  }
  __syncthreads();

  float al[4], be[4];
#pragma unroll
  for (int nt = 0; nt < 4; ++nt) {
    al[nt] = alpha[nt * 16 + l15];
    be[nt] = beta[nt * 16 + l15];
  }

  // ---------------- Phase B: wave w handles c = w ----------------
  f32x4 acc[4] = {};
  const short* vbase = Vt + (((size_t)(w * NHEAD + h) * DKH) << 9) + q * 8;
#pragma unroll 2
  for (int j0 = 0; j0 < SEQ; j0 += 32) {
    bf16x8 ar = *(const bf16x8*)&Rs[l15][j0 + q * 8];
#pragma unroll
    for (int nt = 0; nt < 4; ++nt) {
      bf16x8 bv = *(const bf16x8*)(vbase + (((size_t)(nt * 16 + l15)) << 9) + j0);
      acc[nt] = __builtin_amdgcn_mfma_f32_16x16x32_bf16(ar, bv, acc[nt], 0, 0, 0);
    }
  }

  // softmax(d=64) + LN per row; rows i = q*4+r live in 16-lane groups.
#pragma unroll
  for (int r = 0; r < 4; ++r) {
    float e0 = __expf(acc[0][r]), e1 = __expf(acc[1][r]);
    float e2 = __expf(acc[2][r]), e3 = __expf(acc[3][r]);
    float es = e0 + e1 + e2 + e3;
#pragma unroll
    for (int m = 8; m >= 1; m >>= 1) es += __shfl_xor(es, m);
    const float inv = 1.0f / es;
    const float d0 = e0 * inv - 0.015625f, d1 = e1 * inv - 0.015625f;
    const float d2 = e2 * inv - 0.015625f, d3 = e3 * inv - 0.015625f;
    float sq = d0 * d0 + d1 * d1 + d2 * d2 + d3 * d3;
#pragma unroll
    for (int m = 8; m >= 1; m >>= 1) sq += __shfl_xor(sq, m);
    const float rs = 1.0f / (sqrtf(sq * (1.0f / 63.0f)) + EPSLN);
    float* hr = &hb[(w * 16 + q * 4 + r) * 68 + l15];
    hr[0]  = al[0] * d0 * rs + be[0];
    hr[16] = al[1] * d1 * rs + be[1];
    hr[32] = al[2] * d2 * rs + be[2];
    hr[48] = al[3] * d3 * rs + be[3];
  }
  __syncthreads();

  // Sum the 4 per-wave (per-c) LN outputs + 4*qh residual; store Hc.
  const int ii = tid >> 4, d4 = (tid & 15) * 4;
  float4 s0 = *(float4*)&hb[(0 * 16 + ii) * 68 + d4];
  float4 s1 = *(float4*)&hb[(1 * 16 + ii) * 68 + d4];
  float4 s2 = *(float4*)&hb[(2 * 16 + ii) * 68 + d4];
  float4 s3 = *(float4*)&hb[(3 * 16 + ii) * 68 + d4];
  const float4 qv =
      *(const float4*)&Qp[(size_t)(b * SEQ + i0 + ii) * DMODEL + h * DKH + d4];
  float4 o;
  o.x = s0.x + s1.x + s2.x + s3.x + 4.0f * qv.x;
  o.y = s0.y + s1.y + s2.y + s3.y + 4.0f * qv.y;
  o.z = s0.z + s1.z + s2.z + s3.z + 4.0f * qv.z;
  o.w = s0.w + s1.w + s2.w + s3.w + 4.0f * qv.w;
  *(float4*)&Hc[(size_t)(b * SEQ + i0 + ii) * DMODEL + h * DKH + d4] = o;
}

// ---------------------------------------------------------------------------
extern "C" void kernel_launch(void* const* d_in, const int* in_sizes, int n_in,
                              void* d_out, int out_size, void* d_ws,
                              size_t ws_size, hipStream_t stream) {
  (void)in_sizes; (void)n_in; (void)out_size; (void)ws_size;
  const float* q = (const float*)d_in[0];
  const float* k = (const float*)d_in[1];
  const float* v = (const float*)d_in[2];
  const float* Wq = (const float*)d_in[3];
  const float* bq = (const float*)d_in[4];
  const float* Wk = (const float*)d_in[5];
  const float* bk = (const float*)d_in[6];
  const float* Wv = (const float*)d_in[7];
  const float* bv = (const float*)d_in[8];
  const float* Wo = (const float*)d_in[9];
  const float* bo = (const float*)d_in[10];
  const float* alpha = (const float*)d_in[11];
  const float* beta = (const float*)d_in[12];
  float* out = (float*)d_out;

  // Workspace layout (bytes):
  //   Qp fp32 4MB | Hc fp32 4MB | Kb bf16 2MB | Vt bf16 2MB | 4x Wt bf16 .5MB
  char* wsb = (char*)d_ws;
  float* Qp = (float*)(wsb);
  float* Hc = (float*)(wsb + (4u << 20));
  short* Kb = (short*)(wsb + (8u << 20));
  short* Vtg = (short*)(wsb + (10u << 20));
  short* Wqt = (short*)(wsb + (12u << 20));
  short* Wkt = (short*)(wsb + (12u << 20) + (512u << 10));
  short* Wvt = (short*)(wsb + (13u << 20));
  short* Wot = (short*)(wsb + (13u << 20) + (512u << 10));

  const int M = BSZ * SEQ, N = DMODEL, K = DMODEL;
  wcast_kernel<<<dim3(8, 8, 4), 256, 0, stream>>>(Wq, Wk, Wv, Wo,
                                                  Wqt, Wkt, Wvt, Wot);
  dim3 ggrid(N / 64, M / 64);
  gemm_mfma<0><<<ggrid, 256, 0, stream>>>(q, Wqt, bq, Qp, M, N, K);
  gemm_mfma<1><<<ggrid, 256, 0, stream>>>(k, Wkt, bk, Kb, M, N, K);
  gemm_mfma<2><<<ggrid, 256, 0, stream>>>(v, Wvt, bv, Vtg, M, N, K);
  attn_mfma<<<dim3(SEQ / 16, NHEAD, BSZ), 256, 0, stream>>>(
      Qp, Kb, Vtg, alpha, beta, Hc);
  gemm_mfma<0><<<ggrid, 256, 0, stream>>>(Hc, Wot, bo, out, M, N, K);
}